// Round 1
// baseline (197.971 us; speedup 1.0000x reference)
//
#include <hip/hip_runtime.h>

// Multi-scale deformable attention forward (Deformable-DETR style).
// Shapes fixed by the reference:
//   value:              [16, 8400, 8, 32] fp32
//   value_spatial_shapes [3,2] = (80,80),(40,40),(20,20)  (hardcoded, constant in reference)
//   sampling_locations: [16, 300, 8, 3, 4, 2] fp32 in [0,1]
//   attention_weights:  [16, 300, 8, 3, 4] fp32
//   out:                [16, 300, 256] fp32
#define BS   16
#define LQ   300
#define NH   8
#define C    32
#define NLVL 3
#define NPT  4
#define LV   8400
// position-head stride in float4 units: NH * C/4
#define PH_STRIDE (NH * (C / 4))   // 64

__global__ __launch_bounds__(256) void msda_fwd(
    const float* __restrict__ value,
    const float* __restrict__ loc,
    const float* __restrict__ attw,
    float* __restrict__ out)
{
    const int tid = blockIdx.x * blockDim.x + threadIdx.x;
    const int c4 = tid & 7;               // float4 chunk within 32 channels
    const int h  = (tid >> 3) & (NH - 1); // head
    const int bq = tid >> 6;              // b*LQ + q
    if (bq >= BS * LQ) return;
    const int b = bq / LQ;

    const float* lp = loc  + (size_t)(bq * NH + h) * (NLVL * NPT * 2);
    const float* ap = attw + (size_t)(bq * NH + h) * (NLVL * NPT);

    // base pointer for (b, pos=0, h, c4) in float4 units
    const float4* vb = (const float4*)value
                     + ((size_t)b * LV) * PH_STRIDE + h * (C / 4) + c4;

    float4 acc = make_float4(0.f, 0.f, 0.f, 0.f);

    const int Hs[NLVL] = {80, 40, 20};
    const int Ws[NLVL] = {80, 40, 20};
    const int Os[NLVL] = {0, 6400, 8000};

    #pragma unroll
    for (int l = 0; l < NLVL; ++l) {
        const int H = Hs[l], W = Ws[l];
        const float4* vl = vb + (size_t)Os[l] * PH_STRIDE;
        #pragma unroll
        for (int p = 0; p < NPT; ++p) {
            const float gx = lp[(l * NPT + p) * 2 + 0];
            const float gy = lp[(l * NPT + p) * 2 + 1];
            const float aw = ap[l * NPT + p];

            const float x = gx * (float)W - 0.5f;
            const float y = gy * (float)H - 0.5f;
            const float xf = floorf(x), yf = floorf(y);
            const int x0 = (int)xf, y0 = (int)yf;
            const int x1 = x0 + 1,  y1 = y0 + 1;
            const float lx = x - xf, ly = y - yf;
            const float hx = 1.f - lx, hy = 1.f - ly;

            float w00 = hx * hy * aw;
            float w10 = lx * hy * aw;
            float w01 = hx * ly * aw;
            float w11 = lx * ly * aw;

            const bool vx0 = (unsigned)x0 < (unsigned)W;
            const bool vx1 = (unsigned)x1 < (unsigned)W;
            const bool vy0 = (unsigned)y0 < (unsigned)H;
            const bool vy1 = (unsigned)y1 < (unsigned)H;
            w00 = (vx0 && vy0) ? w00 : 0.f;
            w10 = (vx1 && vy0) ? w10 : 0.f;
            w01 = (vx0 && vy1) ? w01 : 0.f;
            w11 = (vx1 && vy1) ? w11 : 0.f;

            const int xc0 = min(max(x0, 0), W - 1);
            const int xc1 = min(max(x1, 0), W - 1);
            const int yc0 = min(max(y0, 0), H - 1);
            const int yc1 = min(max(y1, 0), H - 1);

            const float4 v00 = vl[(size_t)(yc0 * W + xc0) * PH_STRIDE];
            const float4 v10 = vl[(size_t)(yc0 * W + xc1) * PH_STRIDE];
            const float4 v01 = vl[(size_t)(yc1 * W + xc0) * PH_STRIDE];
            const float4 v11 = vl[(size_t)(yc1 * W + xc1) * PH_STRIDE];

            acc.x += v00.x * w00 + v10.x * w10 + v01.x * w01 + v11.x * w11;
            acc.y += v00.y * w00 + v10.y * w10 + v01.y * w01 + v11.y * w11;
            acc.z += v00.z * w00 + v10.z * w10 + v01.z * w01 + v11.z * w11;
            acc.w += v00.w * w00 + v10.w * w10 + v01.w * w01 + v11.w * w11;
        }
    }

    ((float4*)out)[(size_t)(bq * NH + h) * (C / 4) + c4] = acc;
}

extern "C" void kernel_launch(void* const* d_in, const int* in_sizes, int n_in,
                              void* d_out, int out_size, void* d_ws, size_t ws_size,
                              hipStream_t stream) {
    const float* value = (const float*)d_in[0];
    // d_in[1] = value_spatial_shapes: hardcoded (compile-time constant in reference)
    const float* loc   = (const float*)d_in[2];
    const float* attw  = (const float*)d_in[3];
    float* out = (float*)d_out;

    const int total = BS * LQ * NH * (C / 4);   // 307200 threads
    const int block = 256;
    const int grid  = (total + block - 1) / block;
    msda_fwd<<<grid, block, 0, stream>>>(value, loc, attw, out);
}

// Round 2
// 193.599 us; speedup vs baseline: 1.0226x; 1.0226x over previous
//
#include <hip/hip_runtime.h>

// Multi-scale deformable attention forward.
//   value:              [16, 8400, 8, 32] fp32
//   spatial shapes      (80,80),(40,40),(20,20), offsets 0/6400/8000 (hardcoded)
//   sampling_locations: [16, 300, 8, 3, 4, 2] fp32
//   attention_weights:  [16, 300, 8, 3, 4] fp32
//   out:                [16, 300, 256] fp32
#define BS   16
#define LQ   300
#define NH   8
#define C    32
#define LV   8400
// bytes per position (nH*c*4B)
#define POS_BYTES 1024

__device__ __forceinline__ void sample_point(
    const char* __restrict__ vbase, float gx, float gy, float aw,
    int W, int H, int off, float4& acc)
{
    const float x = gx * (float)W - 0.5f;
    const float y = gy * (float)H - 0.5f;
    const float xf = floorf(x), yf = floorf(y);
    const int x0 = (int)xf, y0 = (int)yf;
    const int x1 = x0 + 1,  y1 = y0 + 1;
    const float lx = x - xf, ly = y - yf;
    const float hx = 1.f - lx, hy = 1.f - ly;

    float w00 = hx * hy * aw;
    float w10 = lx * hy * aw;
    float w01 = hx * ly * aw;
    float w11 = lx * ly * aw;

    const bool vx0 = (unsigned)x0 < (unsigned)W;
    const bool vx1 = (unsigned)x1 < (unsigned)W;
    const bool vy0 = (unsigned)y0 < (unsigned)H;
    const bool vy1 = (unsigned)y1 < (unsigned)H;
    w00 = (vx0 && vy0) ? w00 : 0.f;
    w10 = (vx1 && vy0) ? w10 : 0.f;
    w01 = (vx0 && vy1) ? w01 : 0.f;
    w11 = (vx1 && vy1) ? w11 : 0.f;

    const int xc0 = min(max(x0, 0), W - 1);
    const int xc1 = min(max(x1, 0), W - 1);
    const int yc0 = min(max(y0, 0), H - 1);
    const int yc1 = min(max(y1, 0), H - 1);

    // 32-bit byte offsets (max ~8.6 MB relative to vbase)
    const int r0 = off + yc0 * W;
    const int r1 = off + yc1 * W;
    const float4 v00 = *(const float4*)(vbase + ((r0 + xc0) << 10));
    const float4 v10 = *(const float4*)(vbase + ((r0 + xc1) << 10));
    const float4 v01 = *(const float4*)(vbase + ((r1 + xc0) << 10));
    const float4 v11 = *(const float4*)(vbase + ((r1 + xc1) << 10));

    acc.x += v00.x * w00 + v10.x * w10 + v01.x * w01 + v11.x * w11;
    acc.y += v00.y * w00 + v10.y * w10 + v01.y * w01 + v11.y * w11;
    acc.z += v00.z * w00 + v10.z * w10 + v01.z * w01 + v11.z * w11;
    acc.w += v00.w * w00 + v10.w * w10 + v01.w * w01 + v11.w * w11;
}

// One block (256 thr) per (b,q). Lanes: c4 = t&7, h = (t>>3)&7, point-group
// pg = t>>6 (wave index, uniform per wave). Each wave samples 3 of the 12
// (level,point) pairs; LDS reduce over the 4 waves at the end.
__global__ __launch_bounds__(256, 4) void msda_fwd(
    const float* __restrict__ value,
    const float* __restrict__ loc,
    const float* __restrict__ attw,
    float* __restrict__ out)
{
    __shared__ float4 lds[256];

    const int t  = threadIdx.x;
    const int bq = blockIdx.x;              // b*LQ + q
    const int c4 = t & 7;
    const int h  = (t >> 3) & (NH - 1);
    const int pg = t >> 6;                  // 0..3, wave-uniform
    const int b  = bq / LQ;

    const float2* lp = (const float2*)(loc + (size_t)(bq * NH + h) * 24);
    const float*  ap = attw + (size_t)(bq * NH + h) * 12;
    const char* vbase = (const char*)value
                      + (size_t)b * LV * POS_BYTES + h * (C * 4) + c4 * 16;

    float4 acc = make_float4(0.f, 0.f, 0.f, 0.f);

#define SAMPLE(i, W_, H_, OFF_) do {                         \
        const float2 g = lp[i];                              \
        sample_point(vbase, g.x, g.y, ap[i], W_, H_, OFF_, acc); \
    } while (0)

    switch (pg) {
    case 0: SAMPLE(0, 80, 80, 0);    SAMPLE(1, 80, 80, 0);    SAMPLE(2,  80, 80, 0);    break;
    case 1: SAMPLE(3, 80, 80, 0);    SAMPLE(4, 40, 40, 6400); SAMPLE(5,  40, 40, 6400); break;
    case 2: SAMPLE(6, 40, 40, 6400); SAMPLE(7, 40, 40, 6400); SAMPLE(8,  20, 20, 8000); break;
    default:SAMPLE(9, 20, 20, 8000); SAMPLE(10,20, 20, 8000); SAMPLE(11, 20, 20, 8000); break;
    }
#undef SAMPLE

    lds[t] = acc;
    __syncthreads();

    if (t < 64) {
        float4 a0 = lds[t];
        float4 a1 = lds[t + 64];
        float4 a2 = lds[t + 128];
        float4 a3 = lds[t + 192];
        float4 r;
        r.x = (a0.x + a1.x) + (a2.x + a3.x);
        r.y = (a0.y + a1.y) + (a2.y + a3.y);
        r.z = (a0.z + a1.z) + (a2.z + a3.z);
        r.w = (a0.w + a1.w) + (a2.w + a3.w);
        ((float4*)out)[(size_t)bq * 64 + t] = r;   // (h*8+c4) == t for t<64
    }
}

extern "C" void kernel_launch(void* const* d_in, const int* in_sizes, int n_in,
                              void* d_out, int out_size, void* d_ws, size_t ws_size,
                              hipStream_t stream) {
    const float* value = (const float*)d_in[0];
    // d_in[1] = value_spatial_shapes: compile-time constant in reference
    const float* loc   = (const float*)d_in[2];
    const float* attw  = (const float*)d_in[3];
    float* out = (float*)d_out;

    const int grid = BS * LQ;   // 4800 blocks, one per (b,q)
    msda_fwd<<<grid, 256, 0, stream>>>(value, loc, attw, out);
}